// Round 11
// baseline (12479.861 us; speedup 1.0000x reference)
//
#include <hip/hip_runtime.h>
#include <hip/hip_bf16.h>

// Problem constants: S=512, B=256, E=256, H=256, V=50000
#define SS 512
#define BB 256
#define EE 256
#define HH 256
#define VV 50000
#define NCH 512          // 512 chains = 256 batch x 2 towers
#define VR 16            // emb rows per block in embw GEMM

// Cooperative-grid decomposition: 32 groups x 8 unit-slices = 256 WGs (1/CU).
// Groups are self-organized per-XCD at runtime: 4 groups of 8 WGs per XCD.
#define NGRP 32
#define NSLC 8
#define HWRD (256 * 20)  // 5120 words: h exchange block [blk=kk*8+kq][20] (16 used)

// ctrl[] layout (ints, in ws, zeroed every launch):
#define CTRL_CNT 0       // [0..31]  per-group heavy-path arrive counters
#define CTRL_START 32    //          startup grid barrier counter
#define CTRL_UNSAFE 33   //          grid-uniform fallback flag
#define CTRL_CLAIMG 34   //          global slot claim counter
#define CTRL_CLAIMX 40   // [40..47] per-XCD slot claim counters
#define CTRL_FLAGS 64    // [64..)   fast-path flags: (gid*8+u)*16 stride (64B apart)
#define CTRL_N (64 + NGRP * NSLC * 16)

__device__ __forceinline__ float sigf(float x) { return 1.f / (1.f + __expf(-x)); }
__device__ __forceinline__ float tanhf_fast(float x) { return 1.f - 2.f / (__expf(2.f * x) + 1.f); }

// Pack W[4H][K] row-major into Wp[k][t] = float4{W[t][k], W[H+t][k], W[2H+t][k], W[3H+t][k]}
__global__ void pack_w4(const float* __restrict__ W, float4* __restrict__ Wp, int K) {
    int idx = blockIdx.x * blockDim.x + threadIdx.x;
    if (idx >= K * HH) return;
    int k = idx >> 8, t = idx & 255;
    Wp[idx] = make_float4(W[(0 * HH + t) * K + k], W[(1 * HH + t) * K + k],
                          W[(2 * HH + t) * K + k], W[(3 * HH + t) * K + k]);
}

__global__ void pack_b(const float* __restrict__ bi, const float* __restrict__ bh,
                       float4* __restrict__ bp) {
    int t = threadIdx.x;
    bp[t] = make_float4(bi[0 * HH + t] + bh[0 * HH + t], bi[1 * HH + t] + bh[1 * HH + t],
                        bi[2 * HH + t] + bh[2 * HH + t], bi[3 * HH + t] + bh[3 * HH + t]);
}

__global__ void transpose_w1(const float* __restrict__ W1, float* __restrict__ W1T) {
    int idx = blockIdx.x * blockDim.x + threadIdx.x;
    if (idx >= 2 * HH * HH) return;
    int k = idx >> 8, j = idx & 255;
    W1T[idx] = W1[j * (2 * HH) + k];
}

__global__ void zero_ctrl(int* __restrict__ p) {
    int i = blockIdx.x * blockDim.x + threadIdx.x;
    if (i < CTRL_N) p[i] = 0;
}

// embWp[v][t] = float4 over 4 gates of (emb[v] @ W_ih^T + b_ih + b_hh)
__global__ __launch_bounds__(256) void embw_kernel(const float* __restrict__ emb,
                                                   const float4* __restrict__ Wip,
                                                   const float4* __restrict__ bp,
                                                   float4* __restrict__ embWp) {
    __shared__ float se[VR][EE];
    int t = threadIdx.x;
    int v0 = blockIdx.x * VR;
    for (int r = 0; r < VR; ++r) se[r][t] = emb[(size_t)(v0 + r) * EE + t];
    __syncthreads();
    float4 bb = bp[t];
    float4 acc[VR];
#pragma unroll
    for (int r = 0; r < VR; ++r) acc[r] = bb;
#pragma unroll 2
    for (int k = 0; k < EE; ++k) {
        float4 w = Wip[k * HH + t];
#pragma unroll
        for (int r = 0; r < VR; ++r) {
            float x = se[r][k];
            acc[r].x += w.x * x; acc[r].y += w.y * x;
            acc[r].z += w.z * x; acc[r].w += w.w * x;
        }
    }
    for (int r = 0; r < VR; ++r) embWp[(size_t)(v0 + r) * HH + t] = acc[r];
}

// ---------------------------------------------------------------------------
// Cooperative persistent LSTM, W-in-registers edition.
// Group g owns chains [16g,16g+16). WG (g,u) covers units [32u,32u+32).
// Thread t: wave w=t>>6, lane l=t&63; kq=l>>3 (k-quarter: 32 k-rows),
// jl=l&7; unit gu = u*32 + w*8 + jl. Thread holds W_hh[gates][k-slice] in
// 32 float4 VGPRs (stationary). Per step: h broadcast from LDS (padded
// [kk*8+kq][20w] layout -> kq spans all 32 banks, conflict-free), 2048 FMA,
// then select-exchange butterfly over kq (static reg indices) -> full gates
// for chains {2kq,2kq+1}; pointwise; publish h via XCD-local L2 exchange
// (round-8 proven flag protocol, WRITE_SIZE ~6MB).
// LDS padded >80KB to force 1 WG/CU (co-residency for the spin protocol).
// ---------------------------------------------------------------------------
__global__ __launch_bounds__(256, 1) void lstm_coop(
    const int* __restrict__ s1, const int* __restrict__ s2,
    const float4* __restrict__ Whp, const float4* __restrict__ embWp,
    const float* __restrict__ h0_1, const float* __restrict__ c0_1,
    const float* __restrict__ h0_2, const float* __restrict__ c0_2,
    float* __restrict__ feat, float* __restrict__ hbuf, int* __restrict__ ctrl) {
    __shared__ float hls[16384 + HWRD];  // first 5120 words used; rest = occupancy pad (84KB)
    __shared__ int shi[4];               // gid, u, unsafe

    const int t = threadIdx.x;
    const int w = t >> 6, l = t & 63;
    const int kq = l >> 3, jl = l & 7;

    // ---- startup: claim slot on my physical XCD, grid barrier, pick scheme --
    if (t == 0) {
        // s_getreg HW_REG_XCC_ID (id=20), offset 0, size 32 -> imm 20|(31<<11)
        int my_xcd = (int)__builtin_amdgcn_s_getreg(63508) & 7;
        int slot = atomicAdd(&ctrl[CTRL_CLAIMX + my_xcd], 1);
        int wall = atomicAdd(&ctrl[CTRL_CLAIMG], 1);
        if (slot >= 32)
            __hip_atomic_fetch_or(&ctrl[CTRL_UNSAFE], 1, __ATOMIC_RELAXED,
                                  __HIP_MEMORY_SCOPE_AGENT);
        __hip_atomic_fetch_add(&ctrl[CTRL_START], 1, __ATOMIC_RELEASE,
                               __HIP_MEMORY_SCOPE_AGENT);
        long it = 0;
        while (__hip_atomic_load(&ctrl[CTRL_START], __ATOMIC_ACQUIRE,
                                 __HIP_MEMORY_SCOPE_AGENT) < NGRP * NSLC) {
            if (++it >= 3000000L) break;  // bounded: never hang the queue
            __builtin_amdgcn_s_sleep(2);
        }
        int uns = __hip_atomic_load(&ctrl[CTRL_UNSAFE], __ATOMIC_ACQUIRE,
                                    __HIP_MEMORY_SCOPE_AGENT);
        if (uns) { shi[0] = wall >> 3; shi[1] = wall & 7; }
        else     { shi[0] = my_xcd * 4 + (slot >> 3); shi[1] = slot & 7; }
        shi[2] = uns;
    }
    __syncthreads();
    const int gid = shi[0];
    const int u = shi[1];
    const bool safe = (shi[2] == 0);
    const int gu = u * 32 + w * 8 + jl;  // this thread's unit

    // ---- stationary W_hh slice into registers (32 float4 = 128 VGPR) -------
    float4 wreg[32];
#pragma unroll
    for (int kk = 0; kk < 32; ++kk)
        wreg[kk] = Whp[(kq * 32 + kk) * HH + gu];

    const bool tw2 = gid >= 16;
    const float* h0x = tw2 ? h0_2 : h0_1;
    const float* c0x = tw2 ? c0_2 : c0_1;
    const int* tp = tw2 ? s2 : s1;
    const int gb = (gid & 15) * 16;  // batch base of this group's chains

    // h0 -> LDS mirror (word e = blk*20 + c; blk = kk*8+kq; k = kq*32+kk)
    for (int e = t; e < HWRD; e += 256) {
        int blk = e / 20, cc = e % 20;
        int k = (blk & 7) * 32 + (blk >> 3);
        hls[e] = (cc < 16) ? h0x[(gb + cc) * HH + k] : 0.f;
    }
    float cst[2];
    cst[0] = c0x[(gb + 2 * kq + 0) * HH + gu];
    cst[1] = c0x[(gb + 2 * kq + 1) * HH + gu];
    __syncthreads();

    // x-projection prefetch: this thread needs chains 2kq, 2kq+1 of unit gu
    const int bq0 = gb + 2 * kq;
    float4 pfv[2]; int tnx[2];
    pfv[0] = embWp[(size_t)tp[bq0] * HH + gu];
    pfv[1] = embWp[(size_t)tp[bq0 + 1] * HH + gu];
    tnx[0] = tp[BB + bq0];
    tnx[1] = tp[BB + bq0 + 1];

    const float4* hl4 = (const float4*)hls;
    volatile int* fl = (volatile int*)(ctrl + CTRL_FLAGS + gid * NSLC * 16);
    const int b0 = kq & 1, b1 = (kq >> 1) & 1, b2 = kq >> 2;
    const int blkd = ((gu & 31) * 8 + (gu >> 5)) * 20 + 2 * kq;  // publish word
    int dead = 0;  // sticky bail (t0 only)

    for (int s = 0; s < SS; ++s) {
        // Issue next-step gathers; they retire under the FMA loop (vmcnt FIFO).
        float4 pf2[2]; int t2[2];
        pf2[0] = embWp[(size_t)tnx[0] * HH + gu];
        pf2[1] = embWp[(size_t)tnx[1] * HH + gu];
        int sn = (s + 2 < SS) ? s + 2 : SS - 1;
        t2[0] = tp[sn * BB + bq0];
        t2[1] = tp[sn * BB + bq0 + 1];

        // ---- partial gates: acc[c] = sum_{k in my slice} W[gu][k] * h[c][k]
        float4 acc[16];
#pragma unroll
        for (int c = 0; c < 16; ++c) acc[c] = make_float4(0.f, 0.f, 0.f, 0.f);
#pragma unroll
        for (int kk = 0; kk < 32; ++kk) {       // FULL unroll: wreg stays in regs
            const float4 wv = wreg[kk];
            const int base = (kk * 8 + kq) * 5;  // float4 units (20 words)
            const float4 hv0 = hl4[base + 0], hv1 = hl4[base + 1];
            const float4 hv2 = hl4[base + 2], hv3 = hl4[base + 3];
#define FMA4(C, HV) acc[C].x += wv.x * HV; acc[C].y += wv.y * HV; \
                    acc[C].z += wv.z * HV; acc[C].w += wv.w * HV;
            FMA4(0, hv0.x) FMA4(1, hv0.y) FMA4(2, hv0.z) FMA4(3, hv0.w)
            FMA4(4, hv1.x) FMA4(5, hv1.y) FMA4(6, hv1.z) FMA4(7, hv1.w)
            FMA4(8, hv2.x) FMA4(9, hv2.y) FMA4(10, hv2.z) FMA4(11, hv2.w)
            FMA4(12, hv3.x) FMA4(13, hv3.y) FMA4(14, hv3.z) FMA4(15, hv3.w)
#undef FMA4
        }

        // ---- select-exchange butterfly over kq (lanes stride 8,16,32) ------
        // keeps static register indices everywhere (rule #20)
        float4 s1v[8];
        {
#pragma unroll
            for (int i = 0; i < 8; ++i) {
                constexpr int LO[8] = {0, 1, 4, 5, 8, 9, 12, 13};
                float4 xs = b0 ? acc[LO[i]] : acc[LO[i] + 2];
                float4 kp = b0 ? acc[LO[i] + 2] : acc[LO[i]];
                s1v[i].x = kp.x + __shfl_xor(xs.x, 8);
                s1v[i].y = kp.y + __shfl_xor(xs.y, 8);
                s1v[i].z = kp.z + __shfl_xor(xs.z, 8);
                s1v[i].w = kp.w + __shfl_xor(xs.w, 8);
            }
        }
        float4 s2v[4];
        {
#pragma unroll
            for (int i = 0; i < 4; ++i) {
                constexpr int A2[4] = {0, 1, 4, 5};
                float4 xs = b1 ? s1v[A2[i]] : s1v[A2[i] ^ 2];
                float4 kp = b1 ? s1v[A2[i] ^ 2] : s1v[A2[i]];
                s2v[i].x = kp.x + __shfl_xor(xs.x, 16);
                s2v[i].y = kp.y + __shfl_xor(xs.y, 16);
                s2v[i].z = kp.z + __shfl_xor(xs.z, 16);
                s2v[i].w = kp.w + __shfl_xor(xs.w, 16);
            }
        }
        float4 g2[2];
#pragma unroll
        for (int i = 0; i < 2; ++i) {
            float4 xs = b2 ? s2v[i] : s2v[i + 2];
            float4 kp = b2 ? s2v[i + 2] : s2v[i];
            g2[i].x = kp.x + __shfl_xor(xs.x, 32);
            g2[i].y = kp.y + __shfl_xor(xs.y, 32);
            g2[i].z = kp.z + __shfl_xor(xs.z, 32);
            g2[i].w = kp.w + __shfl_xor(xs.w, 32);
        }

        // ---- pointwise for chains 2kq, 2kq+1 at unit gu ---------------------
        float hn0, hn1;
        {
            g2[0].x += pfv[0].x; g2[0].y += pfv[0].y; g2[0].z += pfv[0].z; g2[0].w += pfv[0].w;
            g2[1].x += pfv[1].x; g2[1].y += pfv[1].y; g2[1].z += pfv[1].z; g2[1].w += pfv[1].w;
            float ig = sigf(g2[0].x), fg = sigf(g2[0].y);
            float gg = tanhf_fast(g2[0].z), og = sigf(g2[0].w);
            cst[0] = fg * cst[0] + ig * gg; hn0 = og * tanhf_fast(cst[0]);
            ig = sigf(g2[1].x); fg = sigf(g2[1].y);
            gg = tanhf_fast(g2[1].z); og = sigf(g2[1].w);
            cst[1] = fg * cst[1] + ig * gg; hn1 = og * tanhf_fast(cst[1]);
        }

        // ---- publish h^{s+1}: one 8B store per thread (XCD L2-resident) -----
        float* hx = hbuf + ((s + 1) & 1) * (NGRP * HWRD) + gid * HWRD;
        *(float2*)(hx + blkd) = make_float2(hn0, hn1);
        __syncthreads();  // drains vmcnt: stores visible in XCD L2
        if (safe) {
            if (t == 0) {
                fl[u * 16] = s + 1;
                if (!dead) {
                    long it = 0;
                    for (;;) {
                        int ok = 1;
#pragma unroll
                        for (int x = 0; x < NSLC; ++x) ok &= (fl[x * 16] >= s + 1);
                        if (ok) break;
                        if (++it >= 400000L) { dead = 1; break; }  // bounded
                    }
                }
            }
        } else {
            __threadfence();
            if (t == 0) {
                atomicAdd(&ctrl[CTRL_CNT + gid], 1);
                int tgt = NSLC * (s + 1);
                if (!dead) {
                    long it = 0;
                    while (__hip_atomic_load(&ctrl[CTRL_CNT + gid], __ATOMIC_RELAXED,
                                             __HIP_MEMORY_SCOPE_AGENT) < tgt) {
                        if (++it >= 4000000L) { dead = 1; break; }
                        __builtin_amdgcn_s_sleep(2);
                    }
                }
            }
        }
        __syncthreads();
        if (!safe) __threadfence();
        // ---- reload group's h^{s+1} -> LDS (lane-linear volatile sc0 loads) -
        const volatile float* hv = (const volatile float*)hx;
#pragma unroll
        for (int q = 0; q < 20; ++q) hls[q * 256 + t] = hv[q * 256 + t];
        __syncthreads();
        pfv[0] = pf2[0]; pfv[1] = pf2[1];
        tnx[0] = t2[0]; tnx[1] = t2[1];
    }

    if (u == 0) {
        for (int e = t; e < HWRD; e += 256) {
            int blk = e / 20, cc = e % 20;
            if (cc < 16) {
                int k = (blk & 7) * 32 + (blk >> 3);
                feat[(size_t)(gid * 16 + cc) * HH + k] = hls[e];
            }
        }
    }
}

// ---------------------------------------------------------------------------
// Fallback streaming LSTM if ws can't hold the embW table.
// ---------------------------------------------------------------------------
#define NBF 4
__global__ __launch_bounds__(256, 1) void lstm_stream(
    const int* __restrict__ s1, const int* __restrict__ s2, const float* __restrict__ emb,
    const float4* __restrict__ Whp, const float4* __restrict__ Wip,
    const float4* __restrict__ bp,
    const float* __restrict__ h0_1, const float* __restrict__ c0_1,
    const float* __restrict__ h0_2, const float* __restrict__ c0_2,
    float* __restrict__ feat) {
    __shared__ float hs[NBF][HH];
    __shared__ float xs[NBF][EE];
    int t = threadIdx.x;
    int ch0 = blockIdx.x * NBF;
    float c[NBF];
    int bat[NBF];
    const int* toks[NBF];
#pragma unroll
    for (int nb = 0; nb < NBF; ++nb) {
        int ch = ch0 + nb;
        bool t2 = ch >= BB;
        int b = t2 ? ch - BB : ch;
        bat[nb] = b;
        toks[nb] = t2 ? s2 : s1;
        hs[nb][t] = (t2 ? h0_2 : h0_1)[b * HH + t];
        c[nb] = (t2 ? c0_2 : c0_1)[b * HH + t];
    }
    __syncthreads();
    for (int s = 0; s < SS; ++s) {
        float4 acc[NBF];
        float4 bb = bp[t];
#pragma unroll
        for (int nb = 0; nb < NBF; ++nb) {
            int tok = toks[nb][s * BB + bat[nb]];
            xs[nb][t] = emb[(size_t)tok * EE + t];
            acc[nb] = bb;
        }
        __syncthreads();
#pragma unroll 4
        for (int k = 0; k < EE; ++k) {
            float4 w = Wip[k * HH + t];
#pragma unroll
            for (int nb = 0; nb < NBF; ++nb) {
                float x = xs[nb][k];
                acc[nb].x += w.x * x; acc[nb].y += w.y * x;
                acc[nb].z += w.z * x; acc[nb].w += w.w * x;
            }
        }
#pragma unroll 8
        for (int k = 0; k < HH; ++k) {
            float4 w = Whp[k * HH + t];
#pragma unroll
            for (int nb = 0; nb < NBF; ++nb) {
                float hk = hs[nb][k];
                acc[nb].x += w.x * hk; acc[nb].y += w.y * hk;
                acc[nb].z += w.z * hk; acc[nb].w += w.w * hk;
            }
        }
        float hnew[NBF];
#pragma unroll
        for (int nb = 0; nb < NBF; ++nb) {
            float ig = sigf(acc[nb].x), fg = sigf(acc[nb].y);
            float gg = tanhf_fast(acc[nb].z), og = sigf(acc[nb].w);
            c[nb] = fg * c[nb] + ig * gg;
            hnew[nb] = og * tanhf_fast(c[nb]);
        }
        __syncthreads();
#pragma unroll
        for (int nb = 0; nb < NBF; ++nb) hs[nb][t] = hnew[nb];
        __syncthreads();
    }
#pragma unroll
    for (int nb = 0; nb < NBF; ++nb) feat[(size_t)(ch0 + nb) * HH + t] = hs[nb][t];
}

__global__ __launch_bounds__(256) void head_kernel(const float* __restrict__ feat,
                                                   const float* __restrict__ W1T,
                                                   const float* __restrict__ b1,
                                                   const float* __restrict__ W2,
                                                   const float* __restrict__ b2,
                                                   float* __restrict__ out) {
    __shared__ float f[2 * HH];
    __shared__ float r0[256], r1[256];
    int j = threadIdx.x;
    int b = blockIdx.x;
    f[j] = feat[(size_t)b * HH + j];
    f[HH + j] = feat[(size_t)(BB + b) * HH + j];
    __syncthreads();
    float acc = b1[j];
#pragma unroll 4
    for (int k = 0; k < 2 * HH; ++k) acc += f[k] * W1T[k * HH + j];
    r0[j] = acc * W2[0 * HH + j];
    r1[j] = acc * W2[1 * HH + j];
    __syncthreads();
    for (int st = 128; st > 0; st >>= 1) {
        if (j < st) { r0[j] += r0[j + st]; r1[j] += r1[j + st]; }
        __syncthreads();
    }
    if (j == 0) {
        out[b * 2 + 0] = r0[0] + b2[0];
        out[b * 2 + 1] = r1[0] + b2[1];
    }
}

extern "C" void kernel_launch(void* const* d_in, const int* in_sizes, int n_in,
                              void* d_out, int out_size, void* d_ws, size_t ws_size,
                              hipStream_t stream) {
    const int* s1 = (const int*)d_in[0];
    const int* s2 = (const int*)d_in[1];
    const float* emb = (const float*)d_in[2];
    const float* W_ih = (const float*)d_in[3];
    const float* W_hh = (const float*)d_in[4];
    const float* b_ih = (const float*)d_in[5];
    const float* b_hh = (const float*)d_in[6];
    const float* h0_1 = (const float*)d_in[7];
    const float* c0_1 = (const float*)d_in[8];
    const float* h0_2 = (const float*)d_in[9];
    const float* c0_2 = (const float*)d_in[10];
    const float* W1 = (const float*)d_in[11];
    const float* b1 = (const float*)d_in[12];
    const float* W2 = (const float*)d_in[13];
    const float* b2 = (const float*)d_in[14];
    float* out = (float*)d_out;

    char* ws = (char*)d_ws;
    size_t off = 0;
    auto alloc = [&](size_t bytes) {
        void* p = ws + off;
        off += (bytes + 255) & ~(size_t)255;
        return p;
    };
    float4* Whp = (float4*)alloc((size_t)HH * HH * sizeof(float4));   // 1MB
    float4* Wip = (float4*)alloc((size_t)EE * HH * sizeof(float4));   // 1MB
    float4* bp = (float4*)alloc(HH * sizeof(float4));
    float* W1T = (float*)alloc((size_t)2 * HH * HH * sizeof(float));  // 512KB
    float* feat = (float*)alloc((size_t)NCH * HH * sizeof(float));    // 512KB
    float* hbuf = (float*)alloc((size_t)2 * NGRP * HWRD * sizeof(float)); // 1.3MB
    int* ctrl = (int*)alloc(CTRL_N * sizeof(int));                    // 20KB
    size_t embw_bytes = (size_t)VV * HH * sizeof(float4);             // 204.8MB
    bool pre = (ws_size >= off + embw_bytes);
    float4* embWp = pre ? (float4*)alloc(embw_bytes) : nullptr;

    pack_w4<<<(HH * HH + 255) / 256, 256, 0, stream>>>(W_ih, Wip, EE);
    pack_w4<<<(HH * HH + 255) / 256, 256, 0, stream>>>(W_hh, Whp, HH);
    pack_b<<<1, 256, 0, stream>>>(b_ih, b_hh, bp);
    transpose_w1<<<(2 * HH * HH + 255) / 256, 256, 0, stream>>>(W1, W1T);

    if (pre) {
        zero_ctrl<<<(CTRL_N + 255) / 256, 256, 0, stream>>>(ctrl);
        embw_kernel<<<VV / VR, 256, 0, stream>>>(emb, Wip, bp, embWp);
        lstm_coop<<<NGRP * NSLC, 256, 0, stream>>>(s1, s2, Whp, embWp,
                                                   h0_1, c0_1, h0_2, c0_2,
                                                   feat, hbuf, ctrl);
    } else {
        lstm_stream<<<NCH / NBF, 256, 0, stream>>>(s1, s2, emb, Whp, Wip, bp,
                                                   h0_1, c0_1, h0_2, c0_2, feat);
    }
    head_kernel<<<BB, 256, 0, stream>>>(feat, W1T, b1, W2, b2, out);
}

// Round 12
// 6124.401 us; speedup vs baseline: 2.0377x; 2.0377x over previous
//
#include <hip/hip_runtime.h>
#include <hip/hip_bf16.h>

// Problem constants: S=512, B=256, E=256, H=256, V=50000
#define SS 512
#define BB 256
#define EE 256
#define HH 256
#define VV 50000
#define NCH 512          // 512 chains = 256 batch x 2 towers
#define VR 16            // emb rows per block in embw GEMM

// Cooperative-grid decomposition: 32 groups x 8 unit-slices = 256 WGs (1/CU).
// Groups are self-organized per-XCD at runtime: 4 groups of 8 WGs per XCD.
#define NGRP 32
#define NSLC 8
#define HWRD (256 * 20)  // 5120 words: h exchange block [blk=kk*8+kq][20] (16 used)

// ctrl[] layout (ints, in ws, zeroed every launch):
#define CTRL_CNT 0       // [0..31]  per-group heavy-path arrive counters
#define CTRL_START 32    //          startup grid barrier counter
#define CTRL_UNSAFE 33   //          grid-uniform fallback flag
#define CTRL_CLAIMG 34   //          global slot claim counter
#define CTRL_CLAIMX 40   // [40..47] per-XCD slot claim counters
#define CTRL_FLAGS 64    // [64..)   fast-path flags: (gid*8+u)*16 stride (64B apart)
#define CTRL_N (64 + NGRP * NSLC * 16)

__device__ __forceinline__ float sigf(float x) { return 1.f / (1.f + __expf(-x)); }
__device__ __forceinline__ float tanhf_fast(float x) { return 1.f - 2.f / (__expf(2.f * x) + 1.f); }

// Pack W[4H][K] row-major into Wp[k][t] = float4{W[t][k], W[H+t][k], W[2H+t][k], W[3H+t][k]}
__global__ void pack_w4(const float* __restrict__ W, float4* __restrict__ Wp, int K) {
    int idx = blockIdx.x * blockDim.x + threadIdx.x;
    if (idx >= K * HH) return;
    int k = idx >> 8, t = idx & 255;
    Wp[idx] = make_float4(W[(0 * HH + t) * K + k], W[(1 * HH + t) * K + k],
                          W[(2 * HH + t) * K + k], W[(3 * HH + t) * K + k]);
}

__global__ void pack_b(const float* __restrict__ bi, const float* __restrict__ bh,
                       float4* __restrict__ bp) {
    int t = threadIdx.x;
    bp[t] = make_float4(bi[0 * HH + t] + bh[0 * HH + t], bi[1 * HH + t] + bh[1 * HH + t],
                        bi[2 * HH + t] + bh[2 * HH + t], bi[3 * HH + t] + bh[3 * HH + t]);
}

__global__ void transpose_w1(const float* __restrict__ W1, float* __restrict__ W1T) {
    int idx = blockIdx.x * blockDim.x + threadIdx.x;
    if (idx >= 2 * HH * HH) return;
    int k = idx >> 8, j = idx & 255;
    W1T[idx] = W1[j * (2 * HH) + k];
}

__global__ void zero_ctrl(int* __restrict__ p) {
    int i = blockIdx.x * blockDim.x + threadIdx.x;
    if (i < CTRL_N) p[i] = 0;
}

// embWp[v][t] = float4 over 4 gates of (emb[v] @ W_ih^T + b_ih + b_hh)
__global__ __launch_bounds__(256) void embw_kernel(const float* __restrict__ emb,
                                                   const float4* __restrict__ Wip,
                                                   const float4* __restrict__ bp,
                                                   float4* __restrict__ embWp) {
    __shared__ float se[VR][EE];
    int t = threadIdx.x;
    int v0 = blockIdx.x * VR;
    for (int r = 0; r < VR; ++r) se[r][t] = emb[(size_t)(v0 + r) * EE + t];
    __syncthreads();
    float4 bb = bp[t];
    float4 acc[VR];
#pragma unroll
    for (int r = 0; r < VR; ++r) acc[r] = bb;
#pragma unroll 2
    for (int k = 0; k < EE; ++k) {
        float4 w = Wip[k * HH + t];
#pragma unroll
        for (int r = 0; r < VR; ++r) {
            float x = se[r][k];
            acc[r].x += w.x * x; acc[r].y += w.y * x;
            acc[r].z += w.z * x; acc[r].w += w.w * x;
        }
    }
    for (int r = 0; r < VR; ++r) embWp[(size_t)(v0 + r) * HH + t] = acc[r];
}

// ---------------------------------------------------------------------------
// Cooperative persistent LSTM, W-in-registers edition (spill-fixed).
// Group g owns chains [16g,16g+16). WG (g,u) covers units [32u,32u+32).
// Thread t: wave w=t>>6, lane l=t&63; kq=l>>3 (k-quarter), jl=l&7;
// unit gu = u*32 + w*8 + jl. Thread holds W_hh[gates][32-k-slice] in 128
// VGPRs (stationary). Register-budget design (VGPR<=~240, NO scratch):
//   - CHUNKED butterfly fold: butterfly is linear in acc, so every 8 kk
//     rows fold acc[16] -> g2[2] and re-zero acc; acc's live range is one
//     chunk, butterfly temps overlap its death.
//   - x-proj prefetch issued AFTER compute (overlaps sync+reload window),
//     so pf2/t2 aren't live across the FMA loop.
// h broadcast from LDS (padded [kk*8+kq][20w]: kq spans all 32 banks);
// publish h via XCD-local L2 flag exchange (round-8 proven protocol).
// LDS padded >80KB to force 1 WG/CU (co-residency for the spin protocol).
// ---------------------------------------------------------------------------
__global__ __launch_bounds__(256, 1) void lstm_coop(
    const int* __restrict__ s1, const int* __restrict__ s2,
    const float4* __restrict__ Whp, const float4* __restrict__ embWp,
    const float* __restrict__ h0_1, const float* __restrict__ c0_1,
    const float* __restrict__ h0_2, const float* __restrict__ c0_2,
    float* __restrict__ feat, float* __restrict__ hbuf, int* __restrict__ ctrl) {
    __shared__ float hls[16384 + HWRD];  // first 5120 words used; rest = occupancy pad (84KB)
    __shared__ int shi[4];               // gid, u, unsafe

    const int t = threadIdx.x;
    const int w = t >> 6, l = t & 63;
    const int kq = l >> 3, jl = l & 7;

    // ---- startup: claim slot on my physical XCD, grid barrier, pick scheme --
    if (t == 0) {
        // s_getreg HW_REG_XCC_ID (id=20), offset 0, size 32 -> imm 20|(31<<11)
        int my_xcd = (int)__builtin_amdgcn_s_getreg(63508) & 7;
        int slot = atomicAdd(&ctrl[CTRL_CLAIMX + my_xcd], 1);
        int wall = atomicAdd(&ctrl[CTRL_CLAIMG], 1);
        if (slot >= 32)
            __hip_atomic_fetch_or(&ctrl[CTRL_UNSAFE], 1, __ATOMIC_RELAXED,
                                  __HIP_MEMORY_SCOPE_AGENT);
        __hip_atomic_fetch_add(&ctrl[CTRL_START], 1, __ATOMIC_RELEASE,
                               __HIP_MEMORY_SCOPE_AGENT);
        long it = 0;
        while (__hip_atomic_load(&ctrl[CTRL_START], __ATOMIC_ACQUIRE,
                                 __HIP_MEMORY_SCOPE_AGENT) < NGRP * NSLC) {
            if (++it >= 3000000L) break;  // bounded: never hang the queue
            __builtin_amdgcn_s_sleep(2);
        }
        int uns = __hip_atomic_load(&ctrl[CTRL_UNSAFE], __ATOMIC_ACQUIRE,
                                    __HIP_MEMORY_SCOPE_AGENT);
        if (uns) { shi[0] = wall >> 3; shi[1] = wall & 7; }
        else     { shi[0] = my_xcd * 4 + (slot >> 3); shi[1] = slot & 7; }
        shi[2] = uns;
    }
    __syncthreads();
    const int gid = shi[0];
    const int u = shi[1];
    const bool safe = (shi[2] == 0);
    const int gu = u * 32 + w * 8 + jl;  // this thread's unit

    // ---- stationary W_hh slice into registers (32 float4 = 128 VGPR) -------
    float4 wreg[32];
#pragma unroll
    for (int kk = 0; kk < 32; ++kk)
        wreg[kk] = Whp[(kq * 32 + kk) * HH + gu];

    const bool tw2 = gid >= 16;
    const float* h0x = tw2 ? h0_2 : h0_1;
    const float* c0x = tw2 ? c0_2 : c0_1;
    const int* tp = tw2 ? s2 : s1;
    const int gb = (gid & 15) * 16;  // batch base of this group's chains

    // h0 -> LDS mirror (word e = blk*20 + c; blk = kk*8+kq; k = kq*32+kk)
    for (int e = t; e < HWRD; e += 256) {
        int blk = e / 20, cc = e % 20;
        int k = (blk & 7) * 32 + (blk >> 3);
        hls[e] = (cc < 16) ? h0x[(gb + cc) * HH + k] : 0.f;
    }
    float cst[2];
    cst[0] = c0x[(gb + 2 * kq + 0) * HH + gu];
    cst[1] = c0x[(gb + 2 * kq + 1) * HH + gu];
    __syncthreads();

    // x-projection prefetch: this thread needs chains 2kq, 2kq+1 of unit gu
    const int bq0 = gb + 2 * kq;
    float4 pfv[2]; int tnx[2];
    pfv[0] = embWp[(size_t)tp[bq0] * HH + gu];
    pfv[1] = embWp[(size_t)tp[bq0 + 1] * HH + gu];
    tnx[0] = tp[BB + bq0];
    tnx[1] = tp[BB + bq0 + 1];

    const float4* hl4 = (const float4*)hls;
    volatile int* fl = (volatile int*)(ctrl + CTRL_FLAGS + gid * NSLC * 16);
    const int b0 = kq & 1, b1 = (kq >> 1) & 1, b2 = kq >> 2;
    const int blkd = ((gu & 31) * 8 + (gu >> 5)) * 20 + 2 * kq;  // publish word
    int dead = 0;  // sticky bail (t0 only)

    for (int s = 0; s < SS; ++s) {
        // ---- gates for all 16 chains, chunked: g2 += butterfly(acc_chunk) --
        float4 g2[2];
        g2[0] = make_float4(0.f, 0.f, 0.f, 0.f);
        g2[1] = make_float4(0.f, 0.f, 0.f, 0.f);
#pragma unroll
        for (int chk = 0; chk < 4; ++chk) {
            float4 acc[16];
#pragma unroll
            for (int c = 0; c < 16; ++c) acc[c] = make_float4(0.f, 0.f, 0.f, 0.f);
#pragma unroll
            for (int k8 = 0; k8 < 8; ++k8) {    // static: wreg stays in regs
                const int kk = chk * 8 + k8;
                const float4 wv = wreg[kk];
                const int base = (kk * 8 + kq) * 5;  // float4 units (20 words)
                const float4 hv0 = hl4[base + 0], hv1 = hl4[base + 1];
                const float4 hv2 = hl4[base + 2], hv3 = hl4[base + 3];
#define FMA4(C, HV) acc[C].x += wv.x * HV; acc[C].y += wv.y * HV; \
                    acc[C].z += wv.z * HV; acc[C].w += wv.w * HV;
                FMA4(0, hv0.x) FMA4(1, hv0.y) FMA4(2, hv0.z) FMA4(3, hv0.w)
                FMA4(4, hv1.x) FMA4(5, hv1.y) FMA4(6, hv1.z) FMA4(7, hv1.w)
                FMA4(8, hv2.x) FMA4(9, hv2.y) FMA4(10, hv2.z) FMA4(11, hv2.w)
                FMA4(12, hv3.x) FMA4(13, hv3.y) FMA4(14, hv3.z) FMA4(15, hv3.w)
#undef FMA4
            }
            // fold: select-exchange butterfly over kq (static reg indices)
            float4 s1v[8];
#pragma unroll
            for (int i = 0; i < 8; ++i) {
                constexpr int LO[8] = {0, 1, 4, 5, 8, 9, 12, 13};
                float4 xs = b0 ? acc[LO[i]] : acc[LO[i] + 2];
                float4 kp = b0 ? acc[LO[i] + 2] : acc[LO[i]];
                s1v[i].x = kp.x + __shfl_xor(xs.x, 8);
                s1v[i].y = kp.y + __shfl_xor(xs.y, 8);
                s1v[i].z = kp.z + __shfl_xor(xs.z, 8);
                s1v[i].w = kp.w + __shfl_xor(xs.w, 8);
            }
            float4 s2v[4];
#pragma unroll
            for (int i = 0; i < 4; ++i) {
                constexpr int A2[4] = {0, 1, 4, 5};
                float4 xs = b1 ? s1v[A2[i]] : s1v[A2[i] ^ 2];
                float4 kp = b1 ? s1v[A2[i] ^ 2] : s1v[A2[i]];
                s2v[i].x = kp.x + __shfl_xor(xs.x, 16);
                s2v[i].y = kp.y + __shfl_xor(xs.y, 16);
                s2v[i].z = kp.z + __shfl_xor(xs.z, 16);
                s2v[i].w = kp.w + __shfl_xor(xs.w, 16);
            }
#pragma unroll
            for (int i = 0; i < 2; ++i) {
                float4 xs = b2 ? s2v[i] : s2v[i + 2];
                float4 kp = b2 ? s2v[i + 2] : s2v[i];
                g2[i].x += kp.x + __shfl_xor(xs.x, 32);
                g2[i].y += kp.y + __shfl_xor(xs.y, 32);
                g2[i].z += kp.z + __shfl_xor(xs.z, 32);
                g2[i].w += kp.w + __shfl_xor(xs.w, 32);
            }
        }

        // ---- issue next-step gathers NOW (overlap sync spin + reload) -------
        float4 pf2[2]; int t2[2];
        pf2[0] = embWp[(size_t)tnx[0] * HH + gu];
        pf2[1] = embWp[(size_t)tnx[1] * HH + gu];
        int sn = (s + 2 < SS) ? s + 2 : SS - 1;
        t2[0] = tp[sn * BB + bq0];
        t2[1] = tp[sn * BB + bq0 + 1];

        // ---- pointwise for chains 2kq, 2kq+1 at unit gu ---------------------
        float hn0, hn1;
        {
            g2[0].x += pfv[0].x; g2[0].y += pfv[0].y; g2[0].z += pfv[0].z; g2[0].w += pfv[0].w;
            g2[1].x += pfv[1].x; g2[1].y += pfv[1].y; g2[1].z += pfv[1].z; g2[1].w += pfv[1].w;
            float ig = sigf(g2[0].x), fg = sigf(g2[0].y);
            float gg = tanhf_fast(g2[0].z), og = sigf(g2[0].w);
            cst[0] = fg * cst[0] + ig * gg; hn0 = og * tanhf_fast(cst[0]);
            ig = sigf(g2[1].x); fg = sigf(g2[1].y);
            gg = tanhf_fast(g2[1].z); og = sigf(g2[1].w);
            cst[1] = fg * cst[1] + ig * gg; hn1 = og * tanhf_fast(cst[1]);
        }

        // ---- publish h^{s+1}: one 8B store per thread (XCD L2-resident) -----
        float* hx = hbuf + ((s + 1) & 1) * (NGRP * HWRD) + gid * HWRD;
        *(float2*)(hx + blkd) = make_float2(hn0, hn1);
        __syncthreads();  // drains vmcnt: stores visible in XCD L2
        if (safe) {
            if (t == 0) {
                fl[u * 16] = s + 1;
                if (!dead) {
                    long it = 0;
                    for (;;) {
                        int ok = 1;
#pragma unroll
                        for (int x = 0; x < NSLC; ++x) ok &= (fl[x * 16] >= s + 1);
                        if (ok) break;
                        if (++it >= 400000L) { dead = 1; break; }  // bounded
                    }
                }
            }
        } else {
            __threadfence();
            if (t == 0) {
                atomicAdd(&ctrl[CTRL_CNT + gid], 1);
                int tgt = NSLC * (s + 1);
                if (!dead) {
                    long it = 0;
                    while (__hip_atomic_load(&ctrl[CTRL_CNT + gid], __ATOMIC_RELAXED,
                                             __HIP_MEMORY_SCOPE_AGENT) < tgt) {
                        if (++it >= 4000000L) { dead = 1; break; }
                        __builtin_amdgcn_s_sleep(2);
                    }
                }
            }
        }
        __syncthreads();
        if (!safe) __threadfence();
        // ---- reload group's h^{s+1} -> LDS (lane-linear volatile sc0 loads) -
        const volatile float* hv = (const volatile float*)hx;
#pragma unroll
        for (int q = 0; q < 20; ++q) hls[q * 256 + t] = hv[q * 256 + t];
        __syncthreads();
        pfv[0] = pf2[0]; pfv[1] = pf2[1];
        tnx[0] = t2[0]; tnx[1] = t2[1];
    }

    if (u == 0) {
        for (int e = t; e < HWRD; e += 256) {
            int blk = e / 20, cc = e % 20;
            if (cc < 16) {
                int k = (blk & 7) * 32 + (blk >> 3);
                feat[(size_t)(gid * 16 + cc) * HH + k] = hls[e];
            }
        }
    }
}

// ---------------------------------------------------------------------------
// Fallback streaming LSTM if ws can't hold the embW table.
// ---------------------------------------------------------------------------
#define NBF 4
__global__ __launch_bounds__(256, 1) void lstm_stream(
    const int* __restrict__ s1, const int* __restrict__ s2, const float* __restrict__ emb,
    const float4* __restrict__ Whp, const float4* __restrict__ Wip,
    const float4* __restrict__ bp,
    const float* __restrict__ h0_1, const float* __restrict__ c0_1,
    const float* __restrict__ h0_2, const float* __restrict__ c0_2,
    float* __restrict__ feat) {
    __shared__ float hs[NBF][HH];
    __shared__ float xs[NBF][EE];
    int t = threadIdx.x;
    int ch0 = blockIdx.x * NBF;
    float c[NBF];
    int bat[NBF];
    const int* toks[NBF];
#pragma unroll
    for (int nb = 0; nb < NBF; ++nb) {
        int ch = ch0 + nb;
        bool t2 = ch >= BB;
        int b = t2 ? ch - BB : ch;
        bat[nb] = b;
        toks[nb] = t2 ? s2 : s1;
        hs[nb][t] = (t2 ? h0_2 : h0_1)[b * HH + t];
        c[nb] = (t2 ? c0_2 : c0_1)[b * HH + t];
    }
    __syncthreads();
    for (int s = 0; s < SS; ++s) {
        float4 acc[NBF];
        float4 bb = bp[t];
#pragma unroll
        for (int nb = 0; nb < NBF; ++nb) {
            int tok = toks[nb][s * BB + bat[nb]];
            xs[nb][t] = emb[(size_t)tok * EE + t];
            acc[nb] = bb;
        }
        __syncthreads();
#pragma unroll 4
        for (int k = 0; k < EE; ++k) {
            float4 w = Wip[k * HH + t];
#pragma unroll
            for (int nb = 0; nb < NBF; ++nb) {
                float x = xs[nb][k];
                acc[nb].x += w.x * x; acc[nb].y += w.y * x;
                acc[nb].z += w.z * x; acc[nb].w += w.w * x;
            }
        }
#pragma unroll 8
        for (int k = 0; k < HH; ++k) {
            float4 w = Whp[k * HH + t];
#pragma unroll
            for (int nb = 0; nb < NBF; ++nb) {
                float hk = hs[nb][k];
                acc[nb].x += w.x * hk; acc[nb].y += w.y * hk;
                acc[nb].z += w.z * hk; acc[nb].w += w.w * hk;
            }
        }
        float hnew[NBF];
#pragma unroll
        for (int nb = 0; nb < NBF; ++nb) {
            float ig = sigf(acc[nb].x), fg = sigf(acc[nb].y);
            float gg = tanhf_fast(acc[nb].z), og = sigf(acc[nb].w);
            c[nb] = fg * c[nb] + ig * gg;
            hnew[nb] = og * tanhf_fast(c[nb]);
        }
        __syncthreads();
#pragma unroll
        for (int nb = 0; nb < NBF; ++nb) hs[nb][t] = hnew[nb];
        __syncthreads();
    }
#pragma unroll
    for (int nb = 0; nb < NBF; ++nb) feat[(size_t)(ch0 + nb) * HH + t] = hs[nb][t];
}

__global__ __launch_bounds__(256) void head_kernel(const float* __restrict__ feat,
                                                   const float* __restrict__ W1T,
                                                   const float* __restrict__ b1,
                                                   const float* __restrict__ W2,
                                                   const float* __restrict__ b2,
                                                   float* __restrict__ out) {
    __shared__ float f[2 * HH];
    __shared__ float r0[256], r1[256];
    int j = threadIdx.x;
    int b = blockIdx.x;
    f[j] = feat[(size_t)b * HH + j];
    f[HH + j] = feat[(size_t)(BB + b) * HH + j];
    __syncthreads();
    float acc = b1[j];
#pragma unroll 4
    for (int k = 0; k < 2 * HH; ++k) acc += f[k] * W1T[k * HH + j];
    r0[j] = acc * W2[0 * HH + j];
    r1[j] = acc * W2[1 * HH + j];
    __syncthreads();
    for (int st = 128; st > 0; st >>= 1) {
        if (j < st) { r0[j] += r0[j + st]; r1[j] += r1[j + st]; }
        __syncthreads();
    }
    if (j == 0) {
        out[b * 2 + 0] = r0[0] + b2[0];
        out[b * 2 + 1] = r1[0] + b2[1];
    }
}

extern "C" void kernel_launch(void* const* d_in, const int* in_sizes, int n_in,
                              void* d_out, int out_size, void* d_ws, size_t ws_size,
                              hipStream_t stream) {
    const int* s1 = (const int*)d_in[0];
    const int* s2 = (const int*)d_in[1];
    const float* emb = (const float*)d_in[2];
    const float* W_ih = (const float*)d_in[3];
    const float* W_hh = (const float*)d_in[4];
    const float* b_ih = (const float*)d_in[5];
    const float* b_hh = (const float*)d_in[6];
    const float* h0_1 = (const float*)d_in[7];
    const float* c0_1 = (const float*)d_in[8];
    const float* h0_2 = (const float*)d_in[9];
    const float* c0_2 = (const float*)d_in[10];
    const float* W1 = (const float*)d_in[11];
    const float* b1 = (const float*)d_in[12];
    const float* W2 = (const float*)d_in[13];
    const float* b2 = (const float*)d_in[14];
    float* out = (float*)d_out;

    char* ws = (char*)d_ws;
    size_t off = 0;
    auto alloc = [&](size_t bytes) {
        void* p = ws + off;
        off += (bytes + 255) & ~(size_t)255;
        return p;
    };
    float4* Whp = (float4*)alloc((size_t)HH * HH * sizeof(float4));   // 1MB
    float4* Wip = (float4*)alloc((size_t)EE * HH * sizeof(float4));   // 1MB
    float4* bp = (float4*)alloc(HH * sizeof(float4));
    float* W1T = (float*)alloc((size_t)2 * HH * HH * sizeof(float));  // 512KB
    float* feat = (float*)alloc((size_t)NCH * HH * sizeof(float));    // 512KB
    float* hbuf = (float*)alloc((size_t)2 * NGRP * HWRD * sizeof(float)); // 1.3MB
    int* ctrl = (int*)alloc(CTRL_N * sizeof(int));                    // 20KB
    size_t embw_bytes = (size_t)VV * HH * sizeof(float4);             // 204.8MB
    bool pre = (ws_size >= off + embw_bytes);
    float4* embWp = pre ? (float4*)alloc(embw_bytes) : nullptr;

    pack_w4<<<(HH * HH + 255) / 256, 256, 0, stream>>>(W_ih, Wip, EE);
    pack_w4<<<(HH * HH + 255) / 256, 256, 0, stream>>>(W_hh, Whp, HH);
    pack_b<<<1, 256, 0, stream>>>(b_ih, b_hh, bp);
    transpose_w1<<<(2 * HH * HH + 255) / 256, 256, 0, stream>>>(W1, W1T);

    if (pre) {
        zero_ctrl<<<(CTRL_N + 255) / 256, 256, 0, stream>>>(ctrl);
        embw_kernel<<<VV / VR, 256, 0, stream>>>(emb, Wip, bp, embWp);
        lstm_coop<<<NGRP * NSLC, 256, 0, stream>>>(s1, s2, Whp, embWp,
                                                   h0_1, c0_1, h0_2, c0_2,
                                                   feat, hbuf, ctrl);
    } else {
        lstm_stream<<<NCH / NBF, 256, 0, stream>>>(s1, s2, emb, Whp, Wip, bp,
                                                   h0_1, c0_1, h0_2, c0_2, feat);
    }
    head_kernel<<<BB, 256, 0, stream>>>(feat, W1T, b1, W2, b2, out);
}